// Round 9
// baseline (112.739 us; speedup 1.0000x reference)
//
#include <hip/hip_runtime.h>
#include <hip/hip_fp16.h>
#include <math.h>

#define PATCH 41
#define PP 1681          // 41*41
#define NB 8
#define STRIDE 10
#define NTH 192          // 3 waves
#define HR 5             // s_H ox-slot stride (4 used + 1 pad; 5 => conflict-free P3)
#define PPB 4            // patches per block (persistent, prefetch-pipelined)
#define TAIL (PP - 8 * NTH)   // 145

typedef float f2v __attribute__((ext_vector_type(2)));

// ---- packed dual-f32 via PLAIN vector ops (R9). R8's hand-rolled VOP3P asm
// (v_pk_add_f32 neg_lo/neg_hi for subtract) corrupted results (absmax 0.336)
// -> modifier semantics unvalidated. LLVM selects v_pk_*_f32 from <2 x float>
// IR with correct encodings; IEEE vector ops are bit-identical to scalar. ----
__device__ __forceinline__ f2v pk_fma(f2v a, f2v b, f2v c) { return __builtin_elementwise_fma(a, b, c); }
__device__ __forceinline__ f2v pk_mul(f2v a, f2v b) { return a * b; }
__device__ __forceinline__ f2v pk_add(f2v a, f2v b) { return a + b; }
__device__ __forceinline__ f2v pk_sub(f2v a, f2v b) { return a - b; }

__device__ __forceinline__ constexpr float tri16(int k) {
    float d = (float)k + 0.5f - 8.0f;
    float a = d < 0.0f ? -d : d;
    return (8.0f - a) * 0.125f;   // == pk[i][j] factor bit-exactly; all values n*2^-4 (exact in f16)
}

__device__ __forceinline__ __half2 u2h2(unsigned v) {
    return __builtin_bit_cast(__half2, v);
}

// lane i <- lane i-1 within its 16-lane DPP row; row-start lanes -> 0
__device__ __forceinline__ unsigned dpp_prev(unsigned v) {
    return (unsigned)__builtin_amdgcn_update_dpp(0, (int)v, 0x111, 0xF, 0xF, true); // row_shr:1
}
// lane i <- lane i+1 within its 16-lane DPP row; row-end lanes -> 0
__device__ __forceinline__ unsigned dpp_next(unsigned v) {
    return (unsigned)__builtin_amdgcn_update_dpp(0, (int)v, 0x101, 0xF, 0xF, true); // row_shl:1
}

// per-pixel select/bin/pack/accumulate (VALIDATED R1-R2; byte-identical logic).
// K is a compile-time literal after unroll -> tri16/ifs fold.
#define SELACC(K, Xv, gyv, axv, ayv, mav, mbv) do {                               \
    bool sw_ = (ayv) > (axv);                                                     \
    bool xn_ = (Xv) < 0.0f;                                                       \
    bool yn_ = (gyv) < 0.0f;                                                      \
    int q_ = (xn_ ? 2 : 0) + ((sw_ != xn_) ? 1 : 0);                              \
    int b0_ = yn_ ? 7 - q_ : q_;                                                  \
    bool f_ = (sw_ != xn_) != yn_;                                                \
    float v0_ = f_ ? (mav) : (mbv);                                               \
    float v1_ = f_ ? (mbv) : (mav);                                               \
    unsigned combo_ = __builtin_bit_cast(unsigned, __builtin_amdgcn_cvt_pkrtz(v0_, v1_)); \
    int sh_ = (b0_ & 3) << 4;                                                     \
    unsigned long long A_ = (unsigned long long)combo_ << sh_;                    \
    unsigned long long B_ = ((b0_ & 3) == 3) ? (unsigned long long)(combo_ >> 16) : 0ull; \
    bool lo_h = b0_ < 4;                                                          \
    unsigned long long lo_ = lo_h ? A_ : B_;                                      \
    unsigned long long hi_ = lo_h ? B_ : A_;                                      \
    uint4 cw_;                                                                    \
    cw_.x = (unsigned)lo_; cw_.y = (unsigned)(lo_ >> 32);                         \
    cw_.z = (unsigned)hi_; cw_.w = (unsigned)(hi_ >> 32);                         \
    const __half2 wo_ = __float2half2_rn(tri16((K) + 4));                         \
    a0 = __hfma2(u2h2(cw_.x), wo_, a0);                                           \
    a1 = __hfma2(u2h2(cw_.y), wo_, a1);                                           \
    a2 = __hfma2(u2h2(cw_.z), wo_, a2);                                           \
    a3 = __hfma2(u2h2(cw_.w), wo_, a3);                                           \
    if ((K) == 1) {                                                               \
        unsigned rx_ = dpp_next(cw_.x);                                           \
        unsigned ry_ = dpp_next(cw_.y);                                           \
        unsigned rz_ = dpp_next(cw_.z);                                           \
        unsigned rw_ = dpp_next(cw_.w);                                           \
        rx_ = ox3 ? 0u : rx_;  ry_ = ox3 ? 0u : ry_;  /* ox3: OOB + junk-src */   \
        rz_ = ox3 ? 0u : rz_;  rw_ = ox3 ? 0u : rw_;                              \
        const __half2 wr_ = __float2half2_rn(tri16(15));                          \
        a0 = __hfma2(u2h2(rx_), wr_, a0);                                         \
        a1 = __hfma2(u2h2(ry_), wr_, a1);                                         \
        a2 = __hfma2(u2h2(rz_), wr_, a2);                                         \
        a3 = __hfma2(u2h2(rw_), wr_, a3);                                         \
    }                                                                             \
    if ((K) >= 6 && (K) < 10) {   /* left lane's k=6..9 ONLY (k=10 dup = R1 bug) */ \
        const __half2 wk_ = wl[(K) - 6];                                          \
        a0 = __hfma2(u2h2(dpp_prev(cw_.x)), wk_, a0);                             \
        a1 = __hfma2(u2h2(dpp_prev(cw_.y)), wk_, a1);                             \
        a2 = __hfma2(u2h2(dpp_prev(cw_.z)), wk_, a2);                             \
        a3 = __hfma2(u2h2(dpp_prev(cw_.w)), wk_, a3);                             \
    }                                                                             \
} while (0)

// R9: pixel-PAIR evaluation, packed math via compiler-selected v_pk_*_f32
// (plain <2 x float> ops; no hand asm). Pairing/indexing/DPP structure
// verified against R7; sync structure unchanged (validated R7).
__global__ __launch_bounds__(NTH, 6) void sift_desc_kernel(
        const float* __restrict__ x,   // [N,1,41,41]
        const float* __restrict__ gk,  // unused: recomputed via exp2
        const float* __restrict__ pk,  // unused: recomputed exactly
        float* __restrict__ out,       // [N,128]
        int n)
{
    const int t = threadIdx.x;
    const int base = blockIdx.x * PPB;

    __shared__ __align__(16) float sA[PP];               // 6.7 KB raw patch buf A
    __shared__ __align__(16) float sB[PP];               // 6.7 KB raw patch buf B
    __shared__ __align__(16) float s_gc[48];             // column gauss
    __shared__ __align__(16) __half s_H[49 * HR * NB];   // 3.9 KB, rows 0-3,45+ zero
    __shared__ float s_desc[128];

    // ---- one-time LUTs ----
    if (t < 48) {
        float dd = (float)(t - 20);
        float g = __builtin_amdgcn_exp2f(dd * dd * -8.582362e-4f);
        s_gc[t] = (t < PATCH) ? g : 0.0f;
    }
    if (t < 160) {                                  // zero H pad rows 0-3,45-48
        int dw = (t < 80) ? t : (820 + t);
        ((unsigned*)s_H)[dw] = 0u;
    }

    // ---- per-thread P1 constants ----
    const int row = t >> 2;
    const int ox  = t & 3;
    const int cb  = ox * STRIDE;
    const bool ox0 = (ox == 0);
    const bool ox3 = (ox == 3);
    const float drow = (float)(row - 20);
    const float rf = __builtin_amdgcn_exp2f(drow * drow * -8.582362e-4f);
    const __half2 z2 = __float2half2_rn(0.0f);
    const __half2 wl[4] = {
        ox0 ? z2 : __float2half2_rn(tri16(0)),
        ox0 ? z2 : __float2half2_rn(tri16(1)),
        ox0 ? z2 : __float2half2_rn(tri16(2)),
        ox0 ? z2 : __float2half2_rn(tri16(3))
    };
    const int rb = row * PATCH + cb;                                      // M row base (col cb)
    const int ru = (row > 0 ? row - 1 : 0) * PATCH + cb;                  // up row
    const int rd = (row < PATCH - 1 ? row + 1 : PATCH - 1) * PATCH + cb;  // down row

    // packed constants (pairs)
    const f2v EPS2 = {1e-10f, 1e-10f};
    const f2v CP5  = {-0.0149238f, -0.0149238f};
    const f2v CP4  = { 0.0670406f,  0.0670406f};
    const f2v CP3  = {-0.1482457f, -0.1482457f};
    const f2v CP2  = { 0.2464287f,  0.2464287f};
    const f2v CP1  = {-0.4235106f, -0.4235106f};
    const f2v CP0  = { 1.2732106f,  1.2732106f};
    const f2v RF2  = {rf, rf};

    // ---- stage patch base+0 into sA ----
    {
        const float* gp = x + (size_t)base * PP;
        float stg[9];
        #pragma unroll
        for (int it = 0; it < 8; ++it) stg[it] = gp[it * NTH + t];
        stg[8] = (t < TAIL) ? gp[8 * NTH + t] : 0.0f;
        #pragma unroll
        for (int it = 0; it < 8; ++it) sA[it * NTH + t] = stg[it];
        if (t < TAIL) sA[8 * NTH + t] = stg[8];
    }
    __syncthreads();

    #pragma unroll
    for (int pi = 0; pi < PPB; ++pi) {
        if (base + pi >= n) break;
        const float* sC = (pi & 1) ? sB : sA;
        float*       sN = (pi & 1) ? sA : sB;
        const bool hn = (pi + 1 < PPB) && (base + pi + 1 < n);

        // -- issue next-patch staging loads EARLY (drain hides under P1) --
        float stg[9];
        if (hn) {
            const float* gp = x + (size_t)(base + pi + 1) * PP;
            #pragma unroll
            for (int it = 0; it < 8; ++it) stg[it] = gp[it * NTH + t];
            stg[8] = (t < TAIL) ? gp[8 * NTH + t] : 0.0f;
        }
        __builtin_amdgcn_sched_barrier(0);   // pin: loads stay above P1

        // ---- P1+P2 fused, owned-pixel scheme, PAIRED arith ----
        if (t < PATCH * 4) {
            // paired preload. m[i]=col cb-1+i (i=0..12): m2[j]={m[2j],m[2j+1]}
            f2v m2[6], u2[5], d2[5], w2[5];
            {
                float mlo = sC[rb - (ox0 ? 0 : 1)];    // clamp == replicate pad
                float mhi = sC[rb];
                f2v v = {mlo, mhi}; m2[0] = v;
            }
            #pragma unroll
            for (int j = 1; j < 6; ++j) { f2v v = {sC[rb + 2*j - 1], sC[rb + 2*j]}; m2[j] = v; }
            const float m12 = sC[rb + (ox3 ? 10 : 11)];
            #pragma unroll
            for (int j = 0; j < 5; ++j) { f2v v = {sC[ru + 2*j], sC[ru + 2*j + 1]}; u2[j] = v; }
            const float u10 = sC[ru + 10];
            #pragma unroll
            for (int j = 0; j < 5; ++j) { f2v v = {sC[rd + 2*j], sC[rd + 2*j + 1]}; d2[j] = v; }
            const float d10 = sC[rd + 10];
            #pragma unroll
            for (int j = 0; j < 5; ++j) w2[j] = pk_mul(*(const f2v*)&s_gc[cb + 2*j], RF2);
            const float w10 = s_gc[cb + 10] * rf;

            __half2 a0 = z2, a1 = z2, a2 = z2, a3 = z2;

            #pragma unroll
            for (int j = 0; j < 5; ++j) {
                f2v gx2 = pk_sub(m2[j + 1], m2[j]);       // gx(2j), gx(2j+1)
                f2v gy2 = pk_sub(d2[j], u2[j]);
                f2v X2  = pk_add(gx2, EPS2);
                f2v t2  = pk_fma(gy2, gy2, EPS2);
                f2v q2  = pk_fma(gx2, gx2, t2);
                f2v sq2 = { __builtin_amdgcn_sqrtf(q2.x), __builtin_amdgcn_sqrtf(q2.y) };
                f2v mg2 = pk_mul(sq2, w2[j]);
                float ax0 = fabsf(X2.x),  ay0 = fabsf(gy2.x);
                float ax1 = fabsf(X2.y),  ay1 = fabsf(gy2.y);
                f2v mn2 = { fminf(ax0, ay0), fminf(ax1, ay1) };
                f2v rc2 = { __builtin_amdgcn_rcpf(fmaxf(fmaxf(ax0, ay0), 1e-30f)),
                            __builtin_amdgcn_rcpf(fmaxf(fmaxf(ax1, ay1), 1e-30f)) };
                f2v r_2 = pk_mul(mn2, rc2);
                f2v rr2 = pk_mul(r_2, r_2);
                f2v p2  = pk_fma(rr2, CP5, CP4);
                p2 = pk_fma(rr2, p2, CP3);
                p2 = pk_fma(rr2, p2, CP2);
                p2 = pk_fma(rr2, p2, CP1);
                p2 = pk_fma(rr2, p2, CP0);
                f2v a42 = pk_mul(p2, r_2);
                f2v ma2 = pk_mul(a42, mg2);
                f2v mb2 = pk_sub(mg2, ma2);
                SELACC(2 * j,     X2.x, gy2.x, ax0, ay0, ma2.x, mb2.x);
                SELACC(2 * j + 1, X2.y, gy2.y, ax1, ay1, ma2.y, mb2.y);
            }
            {   // solo k=10, scalar (original validated path)
                float gx = m12 - m2[5].x;                 // m[12]-m[10]
                float gy = d10 - u10;
                float X  = gx + 1e-10f;
                float mag = __builtin_amdgcn_sqrtf(fmaf(gx, gx, fmaf(gy, gy, 1e-10f))) * w10;
                float ax = fabsf(X), ay = fabsf(gy);
                float r  = fminf(ax, ay) * __builtin_amdgcn_rcpf(fmaxf(fmaxf(ax, ay), 1e-30f));
                float r2 = r * r;
                float a4 = fmaf(r2, -0.0149238f, 0.0670406f);
                a4 = fmaf(r2, a4, -0.1482457f);
                a4 = fmaf(r2, a4, 0.2464287f);
                a4 = fmaf(r2, a4, -0.4235106f);
                a4 = fmaf(r2, a4, 1.2732106f);
                a4 *= r;
                float ma = a4 * mag;
                float mb = mag - ma;
                SELACC(10, X, gy, ax, ay, ma, mb);
            }

            uint4 hv;
            hv.x = __builtin_bit_cast(unsigned, a0);
            hv.y = __builtin_bit_cast(unsigned, a1);
            hv.z = __builtin_bit_cast(unsigned, a2);
            hv.w = __builtin_bit_cast(unsigned, a3);
            *(uint4*)&s_H[((row + 4) * HR + ox) * NB] = hv;   // phys row = row+4
        }

        // -- write staged data LATE (vmcnt wait lands here, after P1) --
        if (hn) {
            #pragma unroll
            for (int it = 0; it < 8; ++it) sN[it * NTH + t] = stg[it];
            if (t < TAIL) sN[8 * NTH + t] = stg[8];
        }
        __syncthreads();

        // ---- P3: vertical pool over zero-padded H ----
        if (t < 128) {
            int b  = t >> 4;
            int oy = (t >> 2) & 3;
            int oxx = t & 3;
            const __half* hp = &s_H[(oy * STRIDE * HR + oxx) * NB + b];
            float v = 0.0f;
            #pragma unroll
            for (int ky = 0; ky < 16; ++ky) {
                v = fmaf(tri16(ky), __half2float(hp[ky * HR * NB]), v);
            }
            s_desc[t] = v;
        }
        __syncthreads();

        // ---- P4: single-wave normalization chain + store ----
        if (t < 64) {
            float a = s_desc[t];
            float b = s_desc[t + 64];

            float ss = fmaf(a, a, b * b);
            #pragma unroll
            for (int o = 32; o > 0; o >>= 1) ss += __shfl_xor(ss, o);
            float inv = 1.0f / fmaxf(__builtin_amdgcn_sqrtf(ss), 1e-12f);
            a = fminf(fmaxf(a * inv, 0.0f), 0.2f);
            b = fminf(fmaxf(b * inv, 0.0f), 0.2f);

            float ss2 = fmaf(a, a, b * b);
            #pragma unroll
            for (int o = 32; o > 0; o >>= 1) ss2 += __shfl_xor(ss2, o);
            float inv2 = 1.0f / fmaxf(__builtin_amdgcn_sqrtf(ss2), 1e-12f);
            a *= inv2; b *= inv2;

            float l1 = a + b;
            #pragma unroll
            for (int o = 32; o > 0; o >>= 1) l1 += __shfl_xor(l1, o);
            float invl = 1.0f / fmaxf(l1, 1e-12f);

            float* op = out + (size_t)(base + pi) * 128;
            op[t]      = __builtin_amdgcn_sqrtf(fmaf(a, invl, 1e-10f));
            op[t + 64] = __builtin_amdgcn_sqrtf(fmaf(b, invl, 1e-10f));
        }
        // next P1 reads sN (complete pre-barrier-1); staging writes sC only
        // after this iter's post-P1 barrier. Race-free (validated R7).
    }
}

extern "C" void kernel_launch(void* const* d_in, const int* in_sizes, int n_in,
                              void* d_out, int out_size, void* d_ws, size_t ws_size,
                              hipStream_t stream) {
    const float* x  = (const float*)d_in[0];
    const float* gk = (const float*)d_in[1];
    const float* pk = (const float*)d_in[2];
    float* out = (float*)d_out;
    const int n = in_sizes[0] / PP;   // 8192 patches
    const int grid = (n + PPB - 1) / PPB;
    sift_desc_kernel<<<grid, NTH, 0, stream>>>(x, gk, pk, out, n);
}